// Round 9
// baseline (231.732 us; speedup 1.0000x reference)
//
#include <hip/hip_runtime.h>
#include <hip/hip_bf16.h>

#define S_LEN 4096
#define E_DIM 512
#define B_DIM 2
#define M_ROWS (B_DIM * S_LEN)   // 8192

typedef __attribute__((ext_vector_type(8))) short short8;   // 8 bf16 = 4 VGPRs
typedef __attribute__((ext_vector_type(4))) float floatx4;  // MFMA C/D

__device__ __forceinline__ unsigned short f2bf(float f) {
    unsigned u = __float_as_uint(f);
    unsigned r = (u + 0x7fffu + ((u >> 16) & 1u)) >> 16;   // RNE
    return (unsigned short)r;
}
__device__ __forceinline__ float bf2f(unsigned short u) {
    return __uint_as_float((unsigned)u << 16);
}

// async 16B/lane global->LDS (lds dest = wave-uniform base + lane*16)
__device__ __forceinline__ void async_copy16(unsigned short* lds, const unsigned short* g) {
    auto gp = (const __attribute__((address_space(1))) unsigned int*)g;
    auto lp = (__attribute__((address_space(3))) unsigned int*)lds;
    __builtin_amdgcn_global_load_lds(gp, lp, 16, 0, 0);
}

// 576 live (tile,ch,bb) blocks; enc = t | ch<<6 | bb<<9
struct MapArg { unsigned short m[576]; };

// ---------------- convert fp32 inputs -> bf16 workspace ----------------
// dstU gets [x | Wq | Wk | Wv] (region later reused for Oh); Wo goes to dstWo.
__global__ __launch_bounds__(256) void convert_bf16(
    const float* __restrict__ x,  const float* __restrict__ wq,
    const float* __restrict__ wk, const float* __restrict__ wv,
    const float* __restrict__ wo, unsigned short* __restrict__ dstU,
    unsigned short* __restrict__ dstWo)
{
    long i = (long)blockIdx.x * 1024 + (long)threadIdx.x * 4;
    const float* src; long off; unsigned short* dst; long doff;
    if      (i < 4194304) { src = x;  off = i;           dst = dstU;  doff = i; }
    else if (i < 4456448) { src = wq; off = i - 4194304; dst = dstU;  doff = i; }
    else if (i < 4718592) { src = wk; off = i - 4456448; dst = dstU;  doff = i; }
    else if (i < 4980736) { src = wv; off = i - 4718592; dst = dstU;  doff = i; }
    else                  { src = wo; off = i - 4980736; dst = dstWo; doff = i - 4980736; }
    float4 v = *(const float4*)(src + off);
    ushort4 o;
    o.x = f2bf(v.x); o.y = f2bf(v.y); o.z = f2bf(v.z); o.w = f2bf(v.w);
    *(ushort4*)(dst + doff) = o;
}

// ---------------- MFMA GEMM core: C[m,n] = sum_k A[m,k]*W[n,k] ----------------
// BK=64: 8 k-steps for K=512. LDS tiles 16B-chunk XOR-swizzled (rule 21).
__device__ __forceinline__ void gemm_core(
    const unsigned short* __restrict__ A, const unsigned short* __restrict__ W,
    void* __restrict__ Cv, const float* __restrict__ bias, int mode,
    int m0, int n0)
{
    __shared__ unsigned short As[128 * 64];   // 16 KB
    __shared__ unsigned short Bs[128 * 64];   // 16 KB
    const int tid = threadIdx.x;
    const int lane = tid & 63, wave = tid >> 6;
    const int wm = wave >> 1, wn = wave & 1;
    const int q4 = lane >> 4, l16 = lane & 15;
    const int er = l16 & 7;                   // read-side swizzle key

    floatx4 acc[4][4];
#pragma unroll
    for (int i = 0; i < 4; ++i)
#pragma unroll
        for (int j = 0; j < 4; ++j) acc[i][j] = (floatx4){0.f, 0.f, 0.f, 0.f};

    const int srow = lane >> 3;               // 0..7
    const int scol = ((lane & 7) ^ srow) << 3;  // inverse-swizzled source col

    for (int k0 = 0; k0 < 512; k0 += 64) {
#pragma unroll
        for (int c = 0; c < 4; ++c) {
            const int rbase = c * 32 + wave * 8;   // covers rows 0..127 in 8-row runs
            async_copy16(&As[rbase * 64],
                         A + (size_t)(m0 + rbase + srow) * 512 + k0 + scol);
            async_copy16(&Bs[rbase * 64],
                         W + (size_t)(n0 + rbase + srow) * 512 + k0 + scol);
        }
        __syncthreads();
        short8 af[4][2], bfr[4][2];
        const int c0 = (q4 ^ er) * 8;         // physical chunk for h=0 (h=1: ^32)
#pragma unroll
        for (int i = 0; i < 4; ++i) {
            const int ra = (wm * 64 + i * 16 + l16) * 64;
            const int rb = (wn * 64 + i * 16 + l16) * 64;
            af[i][0]  = *(const short8*)&As[ra + c0];
            af[i][1]  = *(const short8*)&As[ra + (c0 ^ 32)];
            bfr[i][0] = *(const short8*)&Bs[rb + c0];
            bfr[i][1] = *(const short8*)&Bs[rb + (c0 ^ 32)];
        }
#pragma unroll
        for (int h = 0; h < 2; ++h)
#pragma unroll
            for (int i = 0; i < 4; ++i)
#pragma unroll
                for (int j = 0; j < 4; ++j)
                    acc[i][j] = __builtin_amdgcn_mfma_f32_16x16x32_bf16(
                        af[i][h], bfr[j][h], acc[i][j], 0, 0, 0);
        __syncthreads();
    }

    if (mode == 0) {
        unsigned short* C = (unsigned short*)Cv;
#pragma unroll
        for (int i = 0; i < 4; ++i) {
            int rowb = m0 + wm * 64 + i * 16 + q4 * 4;
#pragma unroll
            for (int j = 0; j < 4; ++j) {
                int col = n0 + wn * 64 + j * 16 + l16;
#pragma unroll
                for (int rg = 0; rg < 4; ++rg)
                    C[(size_t)(rowb + rg) * 512 + col] = f2bf(acc[i][j][rg]);
            }
        }
    } else if (mode == 1) {
        unsigned short* C = (unsigned short*)Cv;
#pragma unroll
        for (int i = 0; i < 4; ++i) {
            int grow = m0 + wm * 64 + i * 16 + q4 * 4;
            int b = grow >> 12, s = grow & 4095;
#pragma unroll
            for (int j = 0; j < 4; ++j) {
                int e = n0 + wn * 64 + j * 16 + l16;
                ushort4 pk;
                pk.x = f2bf(acc[i][j][0]); pk.y = f2bf(acc[i][j][1]);
                pk.z = f2bf(acc[i][j][2]); pk.w = f2bf(acc[i][j][3]);
                *(ushort4*)(C + (size_t)b * 512 * 4096 + (size_t)e * 4096 + s) = pk;
            }
        }
    } else {
        float* C = (float*)Cv;
#pragma unroll
        for (int i = 0; i < 4; ++i) {
            int rowb = m0 + wm * 64 + i * 16 + q4 * 4;
#pragma unroll
            for (int j = 0; j < 4; ++j) {
                int col = n0 + wn * 64 + j * 16 + l16;
                float bv = bias[col];
#pragma unroll
                for (int rg = 0; rg < 4; ++rg)
                    C[(size_t)(rowb + rg) * 512 + col] = acc[i][j][rg] + bv;
            }
        }
    }
}

__global__ __launch_bounds__(256) void gemm_qkv(
    const unsigned short* __restrict__ xb,
    const unsigned short* __restrict__ Wqb, const unsigned short* __restrict__ Wkb,
    const unsigned short* __restrict__ Wvb,
    unsigned short* __restrict__ Qb, unsigned short* __restrict__ Kb,
    unsigned short* __restrict__ Vtb)
{
    const int z = blockIdx.z;
    const unsigned short* W = (z == 0) ? Wqb : (z == 1) ? Wkb : Wvb;
    unsigned short* C = (z == 0) ? Qb : (z == 1) ? Kb : Vtb;
    gemm_core(xb, W, C, nullptr, (z == 2) ? 1 : 0, blockIdx.y * 128, blockIdx.x * 128);
}

__global__ __launch_bounds__(256) void gemm_out(
    const unsigned short* __restrict__ AOb, const unsigned short* __restrict__ Wob,
    const float* __restrict__ bo, float* __restrict__ out)
{
    gemm_core(AOb, Wob, out, bo, 2, blockIdx.y * 128, blockIdx.x * 128);
}

// ---------------- MFMA flash attention, Tm=64, Tn=256, 512 thr ----------------
// Anti-causal (keep j >= i). R9: R5's proven skeleton with DOUBLE keys/step.
// Each wave owns 32 keys (kfA/kfB); the QK loop reads each Q fragment from LDS
// ONCE and feeds TWO MFMAs (Q-LDS traffic per key halved), and total steps
// halve (2112->1056) so per-step phase overhead halves. PV streams V per-kslot
// (8 kslots, 1-ahead prefetch, fully unrolled). XCD map keeps K/V L2-resident.
__global__ __launch_bounds__(512, 2) void flash_mfma(
    const unsigned short* __restrict__ Qg, const unsigned short* __restrict__ Kg,
    const unsigned short* __restrict__ Vt,
    unsigned short* __restrict__ Oh, float* __restrict__ Lb, MapArg map)
{
    const int enc = map.m[blockIdx.x];
    const int tile = enc & 63, ch = (enc >> 6) & 7, bb = enc >> 9;
    const int i0 = tile * 64;
    const int lo0 = 512 * ch, hi = lo0 + 512;
    const int lo = (i0 > lo0) ? i0 : lo0;
    const int lo_al = lo & ~255;            // extra keys < i0 are masked to 0
    const int nsteps = (hi - lo_al) >> 8;   // 1..2

    const int tid = threadIdx.x;
    const int lane = tid & 63, w = tid >> 6;
    const int q4 = lane >> 4, l16 = lane & 15;
    const int e = l16 & 7;                  // Q-swizzle key
    const float scale = 0.044194173824159216f;  // 1/sqrt(512)
    const float MREF = 4.0f;

    __shared__ unsigned short Qs[64 * 512];       // 64 KB, chunk-swizzled
    __shared__ unsigned short Plds[2][64][264];   // 66 KB dbuf, 528B row stride
    __shared__ float Lred[8][64];

    const size_t rowbase = (size_t)bb * S_LEN;
    const size_t vbase   = (size_t)bb * (size_t)512 * 4096;

    // ---- stage Q tile (64 rows x 512 dims) into LDS, chunk-swizzled:
    // LDS 16B-chunk position c of row r holds global chunk (c ^ (r&7)).
#pragma unroll
    for (int rr = 0; rr < 8; ++rr) {
        const int row = w * 8 + rr;
        const unsigned short* src = Qg + (rowbase + i0 + row) * 512
                                    + ((lane ^ (row & 7)) << 3);
        async_copy16(&Qs[row * 512], src);
    }

    floatx4 oacc[4][4];   // rows (mg,q4,rg) x dims [64w + nc*16 + l16]
#pragma unroll
    for (int mg = 0; mg < 4; ++mg)
#pragma unroll
        for (int nc = 0; nc < 4; ++nc) oacc[mg][nc] = (floatx4){0.f, 0.f, 0.f, 0.f};
    float l_acc[4] = {0.f, 0.f, 0.f, 0.f};

    // per-lane swizzled Q read bases (ks even / ks odd)
    const unsigned short* qb0 = &Qs[l16 * 512 + ((q4 ^ e) << 3)];
    const unsigned short* qb1 = &Qs[l16 * 512 + (((q4 + 4) ^ e) << 3)];
    // K bases: this wave's 32 keys (rows j0+32w+l16 and +16), dims q4*8
    const unsigned short* kpbaseA = Kg + (rowbase + 32 * w + l16) * 512 + (q4 << 3);
    const unsigned short* kpbaseB = kpbaseA + (size_t)16 * 512;
    // V base: dim row (64w + nc*16 + l16), keys j0 + kslot*32 + q4*8
    const unsigned short* vpbase = Vt + vbase + (size_t)(w * 64 + l16) * 4096 + (q4 << 3);

    __syncthreads();   // Qs ready (drains the global_load_lds queue)

    for (int t = 0; t < nsteps; ++t) {
        const int j0 = lo_al + t * 256;
        const int buf = t & 1;

        // K frags: 32 keys x full 512 dims for this wave
        short8 kfA[16], kfB[16];
        {
            const unsigned short* kpA = kpbaseA + (size_t)j0 * 512;
            const unsigned short* kpB = kpbaseB + (size_t)j0 * 512;
#pragma unroll
            for (int ks = 0; ks < 16; ++ks) kfA[ks] = *(const short8*)(kpA + ks * 32);
#pragma unroll
            for (int ks = 0; ks < 16; ++ks) kfB[ks] = *(const short8*)(kpB + ks * 32);
        }

        // S^T = K * Q^T full depth: each Q-frag read feeds TWO MFMAs.
        //   keyA = j0+32w+q4*4+rg, keyB = +16, qrow = i0+mg*16+l16
        floatx4 sfA[4], sfB[4];
#pragma unroll
        for (int mg = 0; mg < 4; ++mg) {
            sfA[mg] = (floatx4){0.f, 0.f, 0.f, 0.f};
            sfB[mg] = (floatx4){0.f, 0.f, 0.f, 0.f};
        }
        __builtin_amdgcn_s_setprio(1);
#pragma unroll
        for (int ks = 0; ks < 16; ++ks) {
            const unsigned short* qb = (ks & 1) ? qb1 : qb0;
#pragma unroll
            for (int mg = 0; mg < 4; ++mg) {
                short8 a = *(const short8*)(qb + mg * 8192 + (ks >> 1) * 64);
                sfA[mg] = __builtin_amdgcn_mfma_f32_16x16x32_bf16(kfA[ks], a, sfA[mg], 0, 0, 0);
                sfB[mg] = __builtin_amdgcn_mfma_f32_16x16x32_bf16(kfB[ks], a, sfB[mg], 0, 0, 0);
            }
        }
        __builtin_amdgcn_s_setprio(0);

        // V prefetch for PV kslots 0,1 (in flight under softmax + barrier)
        short8 vc[4], vn[4];
#pragma unroll
        for (int nc = 0; nc < 4; ++nc)
            vc[nc] = *(const short8*)(vpbase + (size_t)(nc * 16) * 4096 + j0);
#pragma unroll
        for (int nc = 0; nc < 4; ++nc)
            vn[nc] = *(const short8*)(vpbase + (size_t)(nc * 16) * 4096 + j0 + 32);

        // in-register softmax (fixed reference MREF) + mask, write P to Plds
        const int kbA = j0 + 32 * w + (q4 << 2);
        const bool full = (j0 >= i0 + 64);   // block-uniform
#pragma unroll
        for (int mg = 0; mg < 4; ++mg) {
            const int row = i0 + mg * 16 + l16;
            float pA0 = __expf(sfA[mg][0] * scale - MREF);
            float pA1 = __expf(sfA[mg][1] * scale - MREF);
            float pA2 = __expf(sfA[mg][2] * scale - MREF);
            float pA3 = __expf(sfA[mg][3] * scale - MREF);
            float pB0 = __expf(sfB[mg][0] * scale - MREF);
            float pB1 = __expf(sfB[mg][1] * scale - MREF);
            float pB2 = __expf(sfB[mg][2] * scale - MREF);
            float pB3 = __expf(sfB[mg][3] * scale - MREF);
            if (!full) {
                pA0 = (kbA + 0 >= row) ? pA0 : 0.f;
                pA1 = (kbA + 1 >= row) ? pA1 : 0.f;
                pA2 = (kbA + 2 >= row) ? pA2 : 0.f;
                pA3 = (kbA + 3 >= row) ? pA3 : 0.f;
                pB0 = (kbA + 16 >= row) ? pB0 : 0.f;
                pB1 = (kbA + 17 >= row) ? pB1 : 0.f;
                pB2 = (kbA + 18 >= row) ? pB2 : 0.f;
                pB3 = (kbA + 19 >= row) ? pB3 : 0.f;
            }
            l_acc[mg] += pA0 + pA1 + pA2 + pA3 + pB0 + pB1 + pB2 + pB3;
            ushort4 pkA, pkB;
            pkA.x = f2bf(pA0); pkA.y = f2bf(pA1); pkA.z = f2bf(pA2); pkA.w = f2bf(pA3);
            pkB.x = f2bf(pB0); pkB.y = f2bf(pB1); pkB.z = f2bf(pB2); pkB.w = f2bf(pB3);
            *(ushort4*)&Plds[buf][mg * 16 + l16][32 * w + (q4 << 2)] = pkA;
            *(ushort4*)&Plds[buf][mg * 16 + l16][32 * w + 16 + (q4 << 2)] = pkB;
        }
        __syncthreads();   // Plds[buf] complete

        // PV: O[rows][64w..64w+64) += P * V, V streamed 1-ahead per kslot
        __builtin_amdgcn_s_setprio(1);
#pragma unroll
        for (int kslot = 0; kslot < 8; ++kslot) {
            if (kslot < 7) {
#pragma unroll
                for (int nc = 0; nc < 4; ++nc)
                    vn[nc] = *(const short8*)(vpbase + (size_t)(nc * 16) * 4096
                                              + j0 + (kslot + 1) * 32);
            }
#pragma unroll
            for (int mg = 0; mg < 4; ++mg) {
                short8 ap = *(const short8*)&Plds[buf][mg * 16 + l16][kslot * 32 + (q4 << 3)];
#pragma unroll
                for (int nc = 0; nc < 4; ++nc)
                    oacc[mg][nc] = __builtin_amdgcn_mfma_f32_16x16x32_bf16(
                        ap, vc[nc], oacc[mg][nc], 0, 0, 0);
            }
#pragma unroll
            for (int nc = 0; nc < 4; ++nc) vc[nc] = vn[nc];
        }
        __builtin_amdgcn_s_setprio(0);
        // next iteration writes Plds[buf^1]: safe without a second barrier
        // (wave X writes buf at step t+2 only after passing barrier(t+1), which
        //  requires every wave to have finished its PV(t) reads of buf).
    }

    // ---- row-sum reduction: l_acc[mg] is row (mg*16+l16) over keys (q4, w)
#pragma unroll
    for (int mg = 0; mg < 4; ++mg) {
        float v = l_acc[mg];
        v += __shfl_xor(v, 16, 64);
        v += __shfl_xor(v, 32, 64);
        if (q4 == 0) Lred[w][mg * 16 + l16] = v;
    }
    __syncthreads();

    const int slot = 8 * ch * (ch + 1) + bb * 8 * (ch + 1) + tile;
    if (tid < 64) {
        float sum = 0.f;
#pragma unroll
        for (int ww = 0; ww < 8; ++ww) sum += Lred[ww][tid];
        Lb[(size_t)slot * 64 + tid] = sum;
    }

    unsigned short* Op = Oh + (size_t)slot * 64 * 512;
#pragma unroll
    for (int mg = 0; mg < 4; ++mg)
#pragma unroll
        for (int nc = 0; nc < 4; ++nc)
#pragma unroll
            for (int rg = 0; rg < 4; ++rg)
                Op[(size_t)(mg * 16 + q4 * 4 + rg) * 512 + w * 64 + nc * 16 + l16]
                    = f2bf(oacc[mg][nc][rg]);
}

// O = (sum_ch Ohat_ch) / (sum_ch l_ch) over valid chunks ch >= i>>9.
// Vectorized (G13): 16B/lane loads per slot, 4 rows per 256-thr block.
__global__ __launch_bounds__(256) void flash_merge(
    const unsigned short* __restrict__ Oh, const float* __restrict__ Lb,
    unsigned short* __restrict__ AO)
{
    const int row = blockIdx.x * 4 + (threadIdx.x >> 6);   // 0..8191
    const int c0 = (threadIdx.x & 63) * 8;                 // col base (8 cols)
    const int bb = row >> 12, i = row & 4095;
    const int t = i >> 6, ri = i & 63;
    const int chmin = i >> 9;
    float lsum = 0.f;
    float v[8] = {0.f, 0.f, 0.f, 0.f, 0.f, 0.f, 0.f, 0.f};
    for (int ch = chmin; ch < 8; ++ch) {
        int slot = 8 * ch * (ch + 1) + bb * 8 * (ch + 1) + t;
        lsum += Lb[(size_t)slot * 64 + ri];
        short8 p = *(const short8*)(Oh + (size_t)slot * 64 * 512
                                    + (size_t)ri * 512 + c0);
#pragma unroll
        for (int k = 0; k < 8; ++k) v[k] += bf2f((unsigned short)p[k]);
    }
    float inv = 1.f / lsum;
    short8 o;
#pragma unroll
    for (int k = 0; k < 8; ++k) o[k] = (short)f2bf(v[k] * inv);
    *(short8*)(AO + (size_t)row * 512 + c0) = o;
}

static MapArg build_map() {
    // XCD-aware placement: position i -> XCD i%8 (round-robin heuristic).
    // XCD x hosts batch bb = x>>2 and chunk pair (7-(x&3), x&3): balanced
    // blocks/steps per XCD; K+V working set ~2MB (L2-fit, proven R4/R5).
    MapArg mp{};
    for (int x = 0; x < 8; ++x) {
        const int bb = x >> 2;
        const int chs[2] = {7 - (x & 3), x & 3};
        int enc[72], st[72], n = 0;
        for (int ci = 0; ci < 2; ++ci) {
            const int ch = chs[ci];
            for (int t = 0; t < 8 * (ch + 1); ++t) {
                int i0 = t * 64, lo0 = 512 * ch, hi = lo0 + 512;
                int lo = (i0 > lo0) ? i0 : lo0;
                int lo_al = lo & ~255;
                enc[n] = t | (ch << 6) | (bb << 9);
                st[n] = (hi - lo_al) >> 8;   // 1..2
                ++n;
            }
        }
        // insertion sort desc by steps (heavy-first LPT within XCD)
        for (int i = 1; i < n; ++i) {
            int ev = enc[i], sv = st[i], j = i - 1;
            while (j >= 0 && st[j] < sv) { st[j + 1] = st[j]; enc[j + 1] = enc[j]; --j; }
            st[j + 1] = sv; enc[j + 1] = ev;
        }
        for (int j = 0; j < n; ++j) mp.m[x + 8 * j] = (unsigned short)enc[j];
    }
    return mp;
}

extern "C" void kernel_launch(void* const* d_in, const int* in_sizes, int n_in,
                              void* d_out, int out_size, void* d_ws, size_t ws_size,
                              hipStream_t stream) {
    (void)in_sizes; (void)n_in; (void)out_size; (void)ws_size;
    const float* x  = (const float*)d_in[0];
    const float* Wq = (const float*)d_in[1];
    const float* Wk = (const float*)d_in[2];
    const float* Wv = (const float*)d_in[3];
    const float* Wo = (const float*)d_in[4];
    const float* bo = (const float*)d_in[5];
    float* out = (float*)d_out;

    // Workspace layout (shorts). Two time-shared regions keep total at 63.59 MB:
    //   QAb: Q during gemm_qkv/flash, then AO during merge/gemm_out (Q dead).
    //   U:   [xb|Wqb|Wkb|Wvb] during convert/gemm_qkv, then Oh (576 slots x
    //        64 x 512 bf16 = 18874368 shorts) during flash/merge.
    unsigned short* ws  = (unsigned short*)d_ws;
    unsigned short* Wob = ws;                       // 262144
    unsigned short* QAb = ws + 262144;              // 4194304 (Q, then AO)
    unsigned short* Kb  = QAb + 4194304;            // 4194304
    unsigned short* Vtb = Kb + 4194304;             // 4194304
    unsigned short* U   = Vtb + 4194304;            // 18874368 (union region)
    unsigned short* xb  = U;
    unsigned short* Wqb = U + 4194304;
    unsigned short* Wkb = Wqb + 262144;
    unsigned short* Wvb = Wkb + 262144;
    unsigned short* Ohb = U;                        // aliases xb+W* (dead by then)
    float* Lbf = (float*)(U + 18874368);            // 576 x 64 floats

    static const MapArg mp = build_map();

    convert_bf16<<<5120, 256, 0, stream>>>(x, Wq, Wk, Wv, Wo, U, Wob);

    gemm_qkv<<<dim3(4, 64, 3), 256, 0, stream>>>(xb, Wqb, Wkb, Wvb, QAb, Kb, Vtb);

    flash_mfma<<<576, 512, 0, stream>>>(QAb, Kb, Vtb, Ohb, Lbf, mp);

    flash_merge<<<2048, 256, 0, stream>>>(Ohb, Lbf, QAb);

    gemm_out<<<dim3(4, 64), 256, 0, stream>>>(QAb, Wob, bo, out);
}

// Round 10
// 213.973 us; speedup vs baseline: 1.0830x; 1.0830x over previous
//
#include <hip/hip_runtime.h>
#include <hip/hip_bf16.h>

#define S_LEN 4096
#define E_DIM 512
#define B_DIM 2
#define M_ROWS (B_DIM * S_LEN)   // 8192

typedef __attribute__((ext_vector_type(8))) short short8;   // 8 bf16 = 4 VGPRs
typedef __attribute__((ext_vector_type(4))) float floatx4;  // MFMA C/D

__device__ __forceinline__ unsigned short f2bf(float f) {
    unsigned u = __float_as_uint(f);
    unsigned r = (u + 0x7fffu + ((u >> 16) & 1u)) >> 16;   // RNE
    return (unsigned short)r;
}
__device__ __forceinline__ float bf2f(unsigned short u) {
    return __uint_as_float((unsigned)u << 16);
}

// async 16B/lane global->LDS (lds dest = wave-uniform base + lane*16)
__device__ __forceinline__ void async_copy16(unsigned short* lds, const unsigned short* g) {
    auto gp = (const __attribute__((address_space(1))) unsigned int*)g;
    auto lp = (__attribute__((address_space(3))) unsigned int*)lds;
    __builtin_amdgcn_global_load_lds(gp, lp, 16, 0, 0);
}

// 576 live (tile,ch,bb) blocks; enc = t | ch<<6 | bb<<9
struct MapArg { unsigned short m[576]; };

// ---------------- convert fp32 inputs -> bf16 workspace ----------------
// dstU gets [x | Wq | Wk | Wv] (region later reused for Oh); Wo goes to dstWo.
__global__ __launch_bounds__(256) void convert_bf16(
    const float* __restrict__ x,  const float* __restrict__ wq,
    const float* __restrict__ wk, const float* __restrict__ wv,
    const float* __restrict__ wo, unsigned short* __restrict__ dstU,
    unsigned short* __restrict__ dstWo)
{
    long i = (long)blockIdx.x * 1024 + (long)threadIdx.x * 4;
    const float* src; long off; unsigned short* dst; long doff;
    if      (i < 4194304) { src = x;  off = i;           dst = dstU;  doff = i; }
    else if (i < 4456448) { src = wq; off = i - 4194304; dst = dstU;  doff = i; }
    else if (i < 4718592) { src = wk; off = i - 4456448; dst = dstU;  doff = i; }
    else if (i < 4980736) { src = wv; off = i - 4718592; dst = dstU;  doff = i; }
    else                  { src = wo; off = i - 4980736; dst = dstWo; doff = i - 4980736; }
    float4 v = *(const float4*)(src + off);
    ushort4 o;
    o.x = f2bf(v.x); o.y = f2bf(v.y); o.z = f2bf(v.z); o.w = f2bf(v.w);
    *(ushort4*)(dst + doff) = o;
}

// ---------------- MFMA GEMM core: C[m,n] = sum_k A[m,k]*W[n,k] ----------------
// BK=64: 8 k-steps for K=512. LDS tiles 16B-chunk XOR-swizzled (rule 21).
__device__ __forceinline__ void gemm_core(
    const unsigned short* __restrict__ A, const unsigned short* __restrict__ W,
    void* __restrict__ Cv, const float* __restrict__ bias, int mode,
    int m0, int n0)
{
    __shared__ unsigned short As[128 * 64];   // 16 KB
    __shared__ unsigned short Bs[128 * 64];   // 16 KB
    const int tid = threadIdx.x;
    const int lane = tid & 63, wave = tid >> 6;
    const int wm = wave >> 1, wn = wave & 1;
    const int q4 = lane >> 4, l16 = lane & 15;
    const int er = l16 & 7;                   // read-side swizzle key

    floatx4 acc[4][4];
#pragma unroll
    for (int i = 0; i < 4; ++i)
#pragma unroll
        for (int j = 0; j < 4; ++j) acc[i][j] = (floatx4){0.f, 0.f, 0.f, 0.f};

    const int srow = lane >> 3;               // 0..7
    const int scol = ((lane & 7) ^ srow) << 3;  // inverse-swizzled source col

    for (int k0 = 0; k0 < 512; k0 += 64) {
#pragma unroll
        for (int c = 0; c < 4; ++c) {
            const int rbase = c * 32 + wave * 8;   // covers rows 0..127 in 8-row runs
            async_copy16(&As[rbase * 64],
                         A + (size_t)(m0 + rbase + srow) * 512 + k0 + scol);
            async_copy16(&Bs[rbase * 64],
                         W + (size_t)(n0 + rbase + srow) * 512 + k0 + scol);
        }
        __syncthreads();
        short8 af[4][2], bfr[4][2];
        const int c0 = (q4 ^ er) * 8;         // physical chunk for h=0 (h=1: ^32)
#pragma unroll
        for (int i = 0; i < 4; ++i) {
            const int ra = (wm * 64 + i * 16 + l16) * 64;
            const int rb = (wn * 64 + i * 16 + l16) * 64;
            af[i][0]  = *(const short8*)&As[ra + c0];
            af[i][1]  = *(const short8*)&As[ra + (c0 ^ 32)];
            bfr[i][0] = *(const short8*)&Bs[rb + c0];
            bfr[i][1] = *(const short8*)&Bs[rb + (c0 ^ 32)];
        }
#pragma unroll
        for (int h = 0; h < 2; ++h)
#pragma unroll
            for (int i = 0; i < 4; ++i)
#pragma unroll
                for (int j = 0; j < 4; ++j)
                    acc[i][j] = __builtin_amdgcn_mfma_f32_16x16x32_bf16(
                        af[i][h], bfr[j][h], acc[i][j], 0, 0, 0);
        __syncthreads();
    }

    if (mode == 0) {
        unsigned short* C = (unsigned short*)Cv;
#pragma unroll
        for (int i = 0; i < 4; ++i) {
            int rowb = m0 + wm * 64 + i * 16 + q4 * 4;
#pragma unroll
            for (int j = 0; j < 4; ++j) {
                int col = n0 + wn * 64 + j * 16 + l16;
#pragma unroll
                for (int rg = 0; rg < 4; ++rg)
                    C[(size_t)(rowb + rg) * 512 + col] = f2bf(acc[i][j][rg]);
            }
        }
    } else if (mode == 1) {
        unsigned short* C = (unsigned short*)Cv;
#pragma unroll
        for (int i = 0; i < 4; ++i) {
            int grow = m0 + wm * 64 + i * 16 + q4 * 4;
            int b = grow >> 12, s = grow & 4095;
#pragma unroll
            for (int j = 0; j < 4; ++j) {
                int e = n0 + wn * 64 + j * 16 + l16;
                ushort4 pk;
                pk.x = f2bf(acc[i][j][0]); pk.y = f2bf(acc[i][j][1]);
                pk.z = f2bf(acc[i][j][2]); pk.w = f2bf(acc[i][j][3]);
                *(ushort4*)(C + (size_t)b * 512 * 4096 + (size_t)e * 4096 + s) = pk;
            }
        }
    } else {
        float* C = (float*)Cv;
#pragma unroll
        for (int i = 0; i < 4; ++i) {
            int rowb = m0 + wm * 64 + i * 16 + q4 * 4;
#pragma unroll
            for (int j = 0; j < 4; ++j) {
                int col = n0 + wn * 64 + j * 16 + l16;
                float bv = bias[col];
#pragma unroll
                for (int rg = 0; rg < 4; ++rg)
                    C[(size_t)(rowb + rg) * 512 + col] = acc[i][j][rg] + bv;
            }
        }
    }
}

__global__ __launch_bounds__(256) void gemm_qkv(
    const unsigned short* __restrict__ xb,
    const unsigned short* __restrict__ Wqb, const unsigned short* __restrict__ Wkb,
    const unsigned short* __restrict__ Wvb,
    unsigned short* __restrict__ Qb, unsigned short* __restrict__ Kb,
    unsigned short* __restrict__ Vtb)
{
    const int z = blockIdx.z;
    const unsigned short* W = (z == 0) ? Wqb : (z == 1) ? Wkb : Wvb;
    unsigned short* C = (z == 0) ? Qb : (z == 1) ? Kb : Vtb;
    gemm_core(xb, W, C, nullptr, (z == 2) ? 1 : 0, blockIdx.y * 128, blockIdx.x * 128);
}

__global__ __launch_bounds__(256) void gemm_out(
    const unsigned short* __restrict__ AOb, const unsigned short* __restrict__ Wob,
    const float* __restrict__ bo, float* __restrict__ out)
{
    gemm_core(AOb, Wob, out, bo, 2, blockIdx.y * 128, blockIdx.x * 128);
}

// ---------------- MFMA flash attention, Tm=64, Tn=128, 512 thr ----------------
// Anti-causal (keep j >= i). Exact R5 step body (91.3us proven: single barrier,
// V loads after QK, sf[4] chains, Plds dbuf) with ALL s_setprio REMOVED:
// in this barrier-locked 2-wave/SIMD structure, prio-1 MFMA regions mutually
// starve the co-resident wave's loads/VALU (m190 regime), serializing the pair.
// XCD map keeps K/V L2-resident (FETCH 91->31MB, R4-proven).
__global__ __launch_bounds__(512, 2) void flash_mfma(
    const unsigned short* __restrict__ Qg, const unsigned short* __restrict__ Kg,
    const unsigned short* __restrict__ Vt,
    unsigned short* __restrict__ Oh, float* __restrict__ Lb, MapArg map)
{
    const int enc = map.m[blockIdx.x];
    const int tile = enc & 63, ch = (enc >> 6) & 7, bb = enc >> 9;
    const int i0 = tile * 64;
    const int lo0 = 512 * ch, hi = lo0 + 512;
    const int lo = (i0 > lo0) ? i0 : lo0;
    const int lo_al = lo & ~127;            // extra keys < i0 are masked to 0
    const int nsteps = (hi - lo_al) >> 7;   // 1..4

    const int tid = threadIdx.x;
    const int lane = tid & 63, w = tid >> 6;
    const int q4 = lane >> 4, l16 = lane & 15;
    const int e = l16 & 7;                  // Q-swizzle key
    const float scale = 0.044194173824159216f;  // 1/sqrt(512)
    const float MREF = 4.0f;

    __shared__ unsigned short Qs[64 * 512];       // 64 KB, chunk-swizzled
    __shared__ unsigned short Plds[2][64][136];   // 34 KB, padded stride
    __shared__ float Lred[8][64];

    const size_t rowbase = (size_t)bb * S_LEN;
    const size_t vbase   = (size_t)bb * (size_t)512 * 4096;

    // ---- stage Q tile (64 rows x 512 dims) into LDS, chunk-swizzled:
    // LDS 16B-chunk position c of row r holds global chunk (c ^ (r&7)).
#pragma unroll
    for (int rr = 0; rr < 8; ++rr) {
        const int row = w * 8 + rr;
        const unsigned short* src = Qg + (rowbase + i0 + row) * 512
                                    + ((lane ^ (row & 7)) << 3);
        async_copy16(&Qs[row * 512], src);
    }

    floatx4 oacc[4][4];   // rows (mg,q4,rg) x dims [64w + nc*16 + l16]
#pragma unroll
    for (int mg = 0; mg < 4; ++mg)
#pragma unroll
        for (int nc = 0; nc < 4; ++nc) oacc[mg][nc] = (floatx4){0.f, 0.f, 0.f, 0.f};
    float l_acc[4] = {0.f, 0.f, 0.f, 0.f};

    // per-lane swizzled Q read bases (ks even / ks odd)
    const unsigned short* qb0 = &Qs[l16 * 512 + ((q4 ^ e) << 3)];
    const unsigned short* qb1 = &Qs[l16 * 512 + (((q4 + 4) ^ e) << 3)];
    // K base: this wave's 16 keys (row = j0 + 16w + l16), dims q4*8
    const unsigned short* kpbase = Kg + (rowbase + 16 * w + l16) * 512 + (q4 << 3);

    __syncthreads();   // Qs ready (drains the global_load_lds queue)

    for (int t = 0; t < nsteps; ++t) {
        const int j0 = lo_al + t * 128;
        const int buf = t & 1;

        // K frags: 16 keys x full 512 dims for this wave
        short8 kf[16];
        const unsigned short* kp = kpbase + (size_t)j0 * 512;
#pragma unroll
        for (int ks = 0; ks < 16; ++ks)
            kf[ks] = *(const short8*)(kp + ks * 32);

        // S^T = K * Q^T full depth: sf[mg] lane(q4,l16):
        //   key = j0+16w+q4*4+rg, qrow = i0+mg*16+l16
        floatx4 sf[4];
#pragma unroll
        for (int mg = 0; mg < 4; ++mg) sf[mg] = (floatx4){0.f, 0.f, 0.f, 0.f};
#pragma unroll
        for (int ks = 0; ks < 16; ++ks) {
            const unsigned short* qb = (ks & 1) ? qb1 : qb0;
#pragma unroll
            for (int mg = 0; mg < 4; ++mg) {
                short8 a = *(const short8*)(qb + mg * 8192 + (ks >> 1) * 64);
                sf[mg] = __builtin_amdgcn_mfma_f32_16x16x32_bf16(kf[ks], a, sf[mg], 0, 0, 0);
            }
        }

        // issue V loads now; they land under softmax + barrier drain
        short8 vf[4][4];   // [nc dim-block][kslot]
#pragma unroll
        for (int nc = 0; nc < 4; ++nc) {
            const unsigned short* vpn = Vt + vbase
                + (size_t)(w * 64 + nc * 16 + l16) * 4096 + j0 + (q4 << 3);
#pragma unroll
            for (int kslot = 0; kslot < 4; ++kslot)
                vf[nc][kslot] = *(const short8*)(vpn + kslot * 32);
        }

        // in-register softmax (fixed reference MREF) + mask, write P to Plds
        const int kb = j0 + 16 * w + (q4 << 2);
        const bool full = (j0 >= i0 + 64);   // block-uniform
#pragma unroll
        for (int mg = 0; mg < 4; ++mg) {
            const int row = i0 + mg * 16 + l16;
            float p0 = __expf(sf[mg][0] * scale - MREF);
            float p1 = __expf(sf[mg][1] * scale - MREF);
            float p2 = __expf(sf[mg][2] * scale - MREF);
            float p3 = __expf(sf[mg][3] * scale - MREF);
            if (!full) {
                p0 = (kb + 0 >= row) ? p0 : 0.f;
                p1 = (kb + 1 >= row) ? p1 : 0.f;
                p2 = (kb + 2 >= row) ? p2 : 0.f;
                p3 = (kb + 3 >= row) ? p3 : 0.f;
            }
            l_acc[mg] += p0 + p1 + p2 + p3;
            ushort4 pk;
            pk.x = f2bf(p0); pk.y = f2bf(p1); pk.z = f2bf(p2); pk.w = f2bf(p3);
            *(ushort4*)&Plds[buf][mg * 16 + l16][16 * w + (q4 << 2)] = pk;
        }
        __syncthreads();   // Plds[buf] complete; also drains vf loads

        // PV: O[rows][64w..64w+64) += P * V
#pragma unroll
        for (int kslot = 0; kslot < 4; ++kslot) {
#pragma unroll
            for (int mg = 0; mg < 4; ++mg) {
                short8 ap = *(const short8*)&Plds[buf][mg * 16 + l16][kslot * 32 + (q4 << 3)];
#pragma unroll
                for (int nc = 0; nc < 4; ++nc)
                    oacc[mg][nc] = __builtin_amdgcn_mfma_f32_16x16x32_bf16(
                        ap, vf[nc][kslot], oacc[mg][nc], 0, 0, 0);
            }
        }
        // next iteration writes Plds[buf^1]: safe without a second barrier
    }

    // ---- row-sum reduction: l_acc[mg] is row (mg*16+l16) over keys (q4, w)
#pragma unroll
    for (int mg = 0; mg < 4; ++mg) {
        float v = l_acc[mg];
        v += __shfl_xor(v, 16, 64);
        v += __shfl_xor(v, 32, 64);
        if (q4 == 0) Lred[w][mg * 16 + l16] = v;
    }
    __syncthreads();

    const int slot = 8 * ch * (ch + 1) + bb * 8 * (ch + 1) + tile;
    if (tid < 64) {
        float sum = 0.f;
#pragma unroll
        for (int ww = 0; ww < 8; ++ww) sum += Lred[ww][tid];
        Lb[(size_t)slot * 64 + tid] = sum;
    }

    unsigned short* Op = Oh + (size_t)slot * 64 * 512;
#pragma unroll
    for (int mg = 0; mg < 4; ++mg)
#pragma unroll
        for (int nc = 0; nc < 4; ++nc)
#pragma unroll
            for (int rg = 0; rg < 4; ++rg)
                Op[(size_t)(mg * 16 + q4 * 4 + rg) * 512 + w * 64 + nc * 16 + l16]
                    = f2bf(oacc[mg][nc][rg]);
}

// O = (sum_ch Ohat_ch) / (sum_ch l_ch) over valid chunks ch >= i>>9.
// Vectorized (G13): 16B/lane loads per slot, 4 rows per 256-thr block.
__global__ __launch_bounds__(256) void flash_merge(
    const unsigned short* __restrict__ Oh, const float* __restrict__ Lb,
    unsigned short* __restrict__ AO)
{
    const int row = blockIdx.x * 4 + (threadIdx.x >> 6);   // 0..8191
    const int c0 = (threadIdx.x & 63) * 8;                 // col base (8 cols)
    const int bb = row >> 12, i = row & 4095;
    const int t = i >> 6, ri = i & 63;
    const int chmin = i >> 9;
    float lsum = 0.f;
    float v[8] = {0.f, 0.f, 0.f, 0.f, 0.f, 0.f, 0.f, 0.f};
    for (int ch = chmin; ch < 8; ++ch) {
        int slot = 8 * ch * (ch + 1) + bb * 8 * (ch + 1) + t;
        lsum += Lb[(size_t)slot * 64 + ri];
        short8 p = *(const short8*)(Oh + (size_t)slot * 64 * 512
                                    + (size_t)ri * 512 + c0);
#pragma unroll
        for (int k = 0; k < 8; ++k) v[k] += bf2f((unsigned short)p[k]);
    }
    float inv = 1.f / lsum;
    short8 o;
#pragma unroll
    for (int k = 0; k < 8; ++k) o[k] = (short)f2bf(v[k] * inv);
    *(short8*)(AO + (size_t)row * 512 + c0) = o;
}

static MapArg build_map() {
    // XCD-aware placement: position i -> XCD i%8 (round-robin heuristic).
    // XCD x hosts batch bb = x>>2 and chunk pair (7-(x&3), x&3).
    // Steps per (bb,ch) = 32ch+20; pairs (ch,7-ch) sum to 264 steps / 72 blocks
    // -> every XCD gets exactly 72 blocks, 264 steps; K+V working set ~2MB (L2-fit).
    MapArg mp{};
    for (int x = 0; x < 8; ++x) {
        const int bb = x >> 2;
        const int chs[2] = {7 - (x & 3), x & 3};
        int enc[72], st[72], n = 0;
        for (int ci = 0; ci < 2; ++ci) {
            const int ch = chs[ci];
            for (int t = 0; t < 8 * (ch + 1); ++t) {
                int i0 = t * 64, lo0 = 512 * ch, hi = lo0 + 512;
                int lo = (i0 > lo0) ? i0 : lo0;
                int lo_al = lo & ~127;
                enc[n] = t | (ch << 6) | (bb << 9);
                st[n] = (hi - lo_al) >> 7;   // 1..4
                ++n;
            }
        }
        // insertion sort desc by steps (heavy-first LPT within XCD)
        for (int i = 1; i < n; ++i) {
            int ev = enc[i], sv = st[i], j = i - 1;
            while (j >= 0 && st[j] < sv) { st[j + 1] = st[j]; enc[j + 1] = enc[j]; --j; }
            st[j + 1] = sv; enc[j + 1] = ev;
        }
        for (int j = 0; j < n; ++j) mp.m[x + 8 * j] = (unsigned short)enc[j];
    }
    return mp;
}

extern "C" void kernel_launch(void* const* d_in, const int* in_sizes, int n_in,
                              void* d_out, int out_size, void* d_ws, size_t ws_size,
                              hipStream_t stream) {
    (void)in_sizes; (void)n_in; (void)out_size; (void)ws_size;
    const float* x  = (const float*)d_in[0];
    const float* Wq = (const float*)d_in[1];
    const float* Wk = (const float*)d_in[2];
    const float* Wv = (const float*)d_in[3];
    const float* Wo = (const float*)d_in[4];
    const float* bo = (const float*)d_in[5];
    float* out = (float*)d_out;

    // Workspace layout (shorts). Two time-shared regions keep total at 63.59 MB:
    //   QAb: Q during gemm_qkv/flash, then AO during merge/gemm_out (Q dead).
    //   U:   [xb|Wqb|Wkb|Wvb] during convert/gemm_qkv, then Oh (576 slots x
    //        64 x 512 bf16 = 18874368 shorts) during flash/merge.
    unsigned short* ws  = (unsigned short*)d_ws;
    unsigned short* Wob = ws;                       // 262144
    unsigned short* QAb = ws + 262144;              // 4194304 (Q, then AO)
    unsigned short* Kb  = QAb + 4194304;            // 4194304
    unsigned short* Vtb = Kb + 4194304;             // 4194304
    unsigned short* U   = Vtb + 4194304;            // 18874368 (union region)
    unsigned short* xb  = U;
    unsigned short* Wqb = U + 4194304;
    unsigned short* Wkb = Wqb + 262144;
    unsigned short* Wvb = Wkb + 262144;
    unsigned short* Ohb = U;                        // aliases xb+W* (dead by then)
    float* Lbf = (float*)(U + 18874368);            // 576 x 64 floats

    static const MapArg mp = build_map();

    convert_bf16<<<5120, 256, 0, stream>>>(x, Wq, Wk, Wv, Wo, U, Wob);

    gemm_qkv<<<dim3(4, 64, 3), 256, 0, stream>>>(xb, Wqb, Wkb, Wvb, QAb, Kb, Vtb);

    flash_mfma<<<576, 512, 0, stream>>>(QAb, Kb, Vtb, Ohb, Lbf, mp);

    flash_merge<<<2048, 256, 0, stream>>>(Ohb, Lbf, QAb);

    gemm_out<<<dim3(4, 64), 256, 0, stream>>>(QAb, Wob, bo, out);
}